// Round 1
// 2370.431 us; speedup vs baseline: 1.8035x; 1.8035x over previous
//
#include <hip/hip_runtime.h>
#include <hip/hip_bf16.h>

// HANConv (HANModel). This round: replace the atomic-scatter edge pipeline
// (edge_pass1/2/3, 128M global f32 atomics per edge type = the 3x832us
// bottleneck) with a CSR build (histogram+scan+reorder) + a gather kernel
// (one wave per dst node, softmax max/sum + weighted accumulation fully in
// registers, single coalesced write of each o row). Runtime dtype detection
// and all downstream GEMM/combine kernels unchanged.

#define HEADS 4
#define DH 32
#define HID 128
#define IN_F 128
#define OUT_F 64
#define NEG 0.2f

typedef unsigned short u16;
typedef unsigned int u32;

__device__ __forceinline__ float us2f(u16 u){ return __uint_as_float(((u32)u) << 16); }
__device__ __forceinline__ u16 f2us(float f){            // f32 -> bf16 RNE
  u32 u = __float_as_uint(f);
  u += 0x7fffu + ((u >> 16) & 1u);
  return (u16)(u >> 16);
}
__device__ __forceinline__ float fin(float v){ return (fabsf(v) < 1e30f) ? v : 0.f; }
// width-adaptive sanitized loads from raw input tensors
__device__ __forceinline__ float ldf(const void* p, size_t i, int wide){
  float v = wide ? ((const float*)p)[i] : us2f(((const u16*)p)[i]);
  return fin(v);
}
__device__ __forceinline__ u16 ld16(const void* p, size_t i, int wide){
  if (wide) return f2us(fin(((const float*)p)[i]));
  u16 r = ((const u16*)p)[i];
  return (((r >> 7) & 0xff) == 0xff) ? (u16)0 : r;   // kill bf16 NaN/Inf
}
__device__ __forceinline__ int ld_idx(const int* __restrict__ p, int e, int sh, int n){
  int v = p[(size_t)e << sh];
  return v < 0 ? 0 : (v >= n ? n - 1 : v);
}

// ---- detection kernels -----------------------------------------------------
// bf16-plausibility of first n u16 words: bf16 data ~100%, f32-as-bf16 ~60%.
__global__ void detect_float_width(const u16* __restrict__ x, int n, int* __restrict__ flag)
{
  __shared__ int cnt;
  if (threadIdx.x == 0) cnt = 0;
  __syncthreads();
  int local = 0;
  for (int i = threadIdx.x; i < n; i += blockDim.x) {
    int e = (x[i] >> 7) & 0xff;
    if (e == 0 || (e >= 100 && e <= 150)) local++;
  }
  atomicAdd(&cnt, local);
  __syncthreads();
  if (threadIdx.x == 0) *flag = (cnt < (n * 9) / 10) ? 1 : 0;  // 1 = f32
}
// int64 indices have all odd int32 words zero (values < 2^31).
__global__ void detect_idx_width(const int* __restrict__ s, int n, int* __restrict__ flag)
{
  __shared__ int any;
  if (threadIdx.x == 0) any = 0;
  __syncthreads();
  for (int i = threadIdx.x; i < n; i += blockDim.x)
    if (s[2 * i + 1] != 0) atomicOr(&any, 1);
  __syncthreads();
  if (threadIdx.x == 0) *flag = any ? 0 : 1;                   // 1 = int64
}

// ---- projection: h[n,c] = x[n,:] @ W[:,c] + b[c]  (->bf16) -----------------
__global__ __launch_bounds__(256) void proj_kernel(
    const void* __restrict__ x, const void* __restrict__ W,
    const void* __restrict__ b, u16* __restrict__ h, int N,
    const int* __restrict__ flag_f)
{
  const int wide = *flag_f;
  __shared__ u16 Wl[IN_F * HID];      // 32 KB
  __shared__ float xt[IN_F][40];      // 20 KB
  for (int i = threadIdx.x; i < IN_F * HID; i += 256) Wl[i] = ld16(W, i, wide);
  const int base = blockIdx.x * 32;
  for (int i = threadIdx.x; i < 32 * IN_F; i += 256) {
    int node = i >> 7, k = i & 127;
    int nn = base + node;
    xt[k][node] = (nn < N) ? ldf(x, (size_t)nn * IN_F + k, wide) : 0.f;
  }
  __syncthreads();
  const int ng = threadIdx.x & 7;
  const int cg = threadIdx.x >> 3;
  float acc[4][4];
#pragma unroll
  for (int r = 0; r < 4; ++r)
#pragma unroll
    for (int j = 0; j < 4; ++j) acc[r][j] = ldf(b, cg * 4 + j, wide);
#pragma unroll 4
  for (int k = 0; k < IN_F; ++k) {
    const float4 xv = *(const float4*)&xt[k][ng * 4];
    const ushort4 wv = *(const ushort4*)&Wl[k * HID + cg * 4];
    const float w0 = us2f(wv.x), w1 = us2f(wv.y), w2 = us2f(wv.z), w3 = us2f(wv.w);
    acc[0][0] += xv.x * w0; acc[0][1] += xv.x * w1; acc[0][2] += xv.x * w2; acc[0][3] += xv.x * w3;
    acc[1][0] += xv.y * w0; acc[1][1] += xv.y * w1; acc[1][2] += xv.y * w2; acc[1][3] += xv.y * w3;
    acc[2][0] += xv.z * w0; acc[2][1] += xv.z * w1; acc[2][2] += xv.z * w2; acc[2][3] += xv.z * w3;
    acc[3][0] += xv.w * w0; acc[3][1] += xv.w * w1; acc[3][2] += xv.w * w2; acc[3][3] += xv.w * w3;
  }
#pragma unroll
  for (int r = 0; r < 4; ++r) {
    int nn = base + ng * 4 + r;
    if (nn < N) {
      ushort4 o;
      o.x = f2us(acc[r][0]); o.y = f2us(acc[r][1]);
      o.z = f2us(acc[r][2]); o.w = f2us(acc[r][3]);
      *(ushort4*)&h[(size_t)nn * HID + cg * 4] = o;
    }
  }
}

// ---- per-node logits for two att vectors -----------------------------------
__global__ __launch_bounds__(256) void compute_a2(
    const u16* __restrict__ h, const void* __restrict__ att1,
    const void* __restrict__ att2, float* __restrict__ a1,
    float* __restrict__ a2, int N, const int* __restrict__ flag_f)
{
  const int wide = *flag_f;
  __shared__ float s1[HID], s2[HID];
  if (threadIdx.x < HID) {
    s1[threadIdx.x] = ldf(att1, threadIdx.x, wide);
    s2[threadIdx.x] = ldf(att2, threadIdx.x, wide);
  }
  __syncthreads();
  int t = blockIdx.x * 256 + threadIdx.x;
  if (t >= N * HEADS) return;
  int n = t >> 2, hh = t & 3;
  const u16* p = h + (size_t)n * HID + hh * DH;
  float acc1 = 0.f, acc2 = 0.f;
#pragma unroll
  for (int d = 0; d < DH; ++d) {
    float f = us2f(p[d]);
    acc1 += f * s1[hh * DH + d];
    acc2 += f * s2[hh * DH + d];
  }
  a1[t] = acc1;
  a2[t] = acc2;
}

// ---- CSR build -------------------------------------------------------------
__global__ __launch_bounds__(256) void hist_kernel(
    const int* __restrict__ dst, int E, const int* __restrict__ flag_i,
    int Nd, int* __restrict__ deg)
{
  int e = blockIdx.x * 256 + threadIdx.x;
  if (e >= E) return;
  int sh = *flag_i;
  int d = ld_idx(dst, e, sh, Nd);
  atomicAdd(&deg[d], 1);
}

// per-block (1024-elem) exclusive scan; block totals to blksum
__global__ __launch_bounds__(256) void scan1_kernel(
    const int* __restrict__ deg, int Nd, int* __restrict__ rowptr,
    int* __restrict__ blksum)
{
  __shared__ int ssum[256];
  int base = blockIdx.x * 1024;
  int t = threadIdx.x;
  int idx0 = base + t * 4;
  int v[4];
#pragma unroll
  for (int j = 0; j < 4; ++j) v[j] = (idx0 + j < Nd) ? deg[idx0 + j] : 0;
  int tsum = v[0] + v[1] + v[2] + v[3];
  ssum[t] = tsum;
  __syncthreads();
  for (int ofs = 1; ofs < 256; ofs <<= 1) {
    int x = (t >= ofs) ? ssum[t - ofs] : 0;
    __syncthreads();
    ssum[t] += x;
    __syncthreads();
  }
  if (t == 255) blksum[blockIdx.x] = ssum[255];
  int run = ssum[t] - tsum;   // exclusive offset within block
#pragma unroll
  for (int j = 0; j < 4; ++j) {
    if (idx0 + j < Nd) rowptr[idx0 + j] = run;
    run += v[j];
  }
}

// exclusive scan of block sums (nb <= ~200, sequential is fine)
__global__ void scan2_kernel(int* __restrict__ blksum, int nb)
{
  if (threadIdx.x == 0 && blockIdx.x == 0) {
    int run = 0;
    for (int b = 0; b < nb; ++b) { int t = blksum[b]; blksum[b] = run; run += t; }
  }
}

__global__ __launch_bounds__(256) void scan3_kernel(
    int* __restrict__ rowptr, int* __restrict__ cursor,
    const int* __restrict__ blksum, int Nd, int E)
{
  int i = blockIdx.x * 256 + threadIdx.x;
  if (i < Nd) {
    int v = rowptr[i] + blksum[i >> 10];
    rowptr[i] = v;
    cursor[i] = v;
  }
  if (i == 0) rowptr[Nd] = E;
}

__global__ __launch_bounds__(256) void reorder_kernel(
    const int* __restrict__ src, const int* __restrict__ dst, int E,
    const int* __restrict__ flag_i, int Ns, int Nd,
    int* __restrict__ cursor, int* __restrict__ csr_src)
{
  int e = blockIdx.x * 256 + threadIdx.x;
  if (e >= E) return;
  int sh = *flag_i;
  int d = ld_idx(dst, e, sh, Nd);
  int s = ld_idx(src, e, sh, Ns);
  int pos = atomicAdd(&cursor[d], 1);
  csr_src[pos] = s;
}

// ---- gather edge conv: one wave per dst node, lane = 2 channels ------------
// Two passes over the node's in-edge list (register resident softmax):
//   pass A: m = max over edges of leakyrelu(a_s[s]+a_d[d])
//   pass B: num += exp(al-m)*h_src[s], den += exp(al-m)
// write o[row] = num/(den+1e-16) once. No atomics, no o memset needed.
__global__ __launch_bounds__(256) void gather_conv(
    const int* __restrict__ rowptr, const int* __restrict__ csr_src,
    const float* __restrict__ a_s, const float* __restrict__ a_d,
    const u16* __restrict__ h_src, float* __restrict__ o,
    int lo, int rows)
{
  int wid = (blockIdx.x * 256 + threadIdx.x) >> 6;
  if (wid >= rows) return;
  int n = lo + wid;
  int lane = threadIdx.x & 63;
  int hh = lane >> 4;
  int start = rowptr[n], end = rowptr[n + 1];
  float ad = a_d[n * HEADS + hh];
  float m = -1e30f;
  for (int e = start; e < end; ++e) {
    int s = csr_src[e];
    float al = a_s[s * HEADS + hh] + ad;
    al = (al > 0.f) ? al : NEG * al;
    m = fmaxf(m, al);
  }
  float den = 0.f, n0 = 0.f, n1 = 0.f;
  for (int e = start; e < end; ++e) {
    int s = csr_src[e];
    float al = a_s[s * HEADS + hh] + ad;
    al = (al > 0.f) ? al : NEG * al;
    float ex = __expf(al - m);
    den += ex;
    const u16* hp = h_src + (size_t)s * HID + 2 * lane;
    n0 += ex * us2f(hp[0]);
    n1 += ex * us2f(hp[1]);
  }
  float inv = 1.f / (den + 1e-16f);
  float* op = o + (size_t)wid * HID + 2 * lane;
  op[0] = n0 * inv;
  op[1] = n1 * inv;
}

// ---- semantic colsum over a chunk: S[c] += sum_n tanh(relu(o)@Wk + bk) -----
__global__ __launch_bounds__(256) void colsum_chunk(
    const float* __restrict__ o, int rows, const void* __restrict__ Wk,
    const void* __restrict__ bk, float* __restrict__ S,
    const int* __restrict__ flag_f)
{
  const int wide = *flag_f;
  __shared__ u16 Wl[HID * HID];   // 32 KB
  __shared__ float xt[HID][40];   // 20 KB
  for (int i = threadIdx.x; i < HID * HID; i += 256) Wl[i] = ld16(Wk, i, wide);
  const int ng = threadIdx.x & 7, cg = threadIdx.x >> 3;
  float bc[4], sum[4] = {0.f, 0.f, 0.f, 0.f};
#pragma unroll
  for (int j = 0; j < 4; ++j) bc[j] = ldf(bk, cg * 4 + j, wide);

  int ntiles = (rows + 31) >> 5;
  for (int t = blockIdx.x; t < ntiles; t += gridDim.x) {
    int base = t << 5;
    __syncthreads();
    for (int i = threadIdx.x; i < 32 * HID; i += 256) {
      int node = i >> 7, k = i & 127;
      int nn = base + node;
      xt[k][node] = (nn < rows) ? fmaxf(o[(size_t)nn * HID + k], 0.f) : 0.f;
    }
    __syncthreads();
    float acc[4][4];
#pragma unroll
    for (int r = 0; r < 4; ++r)
#pragma unroll
      for (int j = 0; j < 4; ++j) acc[r][j] = bc[j];
#pragma unroll 4
    for (int k = 0; k < HID; ++k) {
      const float4 xv = *(const float4*)&xt[k][ng * 4];
      const ushort4 wv = *(const ushort4*)&Wl[k * HID + cg * 4];
      const float w0 = us2f(wv.x), w1 = us2f(wv.y), w2 = us2f(wv.z), w3 = us2f(wv.w);
      acc[0][0] += xv.x * w0; acc[0][1] += xv.x * w1; acc[0][2] += xv.x * w2; acc[0][3] += xv.x * w3;
      acc[1][0] += xv.y * w0; acc[1][1] += xv.y * w1; acc[1][2] += xv.y * w2; acc[1][3] += xv.y * w3;
      acc[2][0] += xv.z * w0; acc[2][1] += xv.z * w1; acc[2][2] += xv.z * w2; acc[2][3] += xv.z * w3;
      acc[3][0] += xv.w * w0; acc[3][1] += xv.w * w1; acc[3][2] += xv.w * w2; acc[3][3] += xv.w * w3;
    }
#pragma unroll
    for (int r = 0; r < 4; ++r) {
      if (base + ng * 4 + r < rows) {
#pragma unroll
        for (int j = 0; j < 4; ++j) sum[j] += tanhf(acc[r][j]);
      }
    }
  }
#pragma unroll
  for (int j = 0; j < 4; ++j) {
    float v = sum[j];
    v += __shfl_xor(v, 1);
    v += __shfl_xor(v, 2);
    v += __shfl_xor(v, 4);
    if (ng == 0) atomicAdd(&S[cg * 4 + j], v);
  }
}

// ---- P = relu(o_chunk) @ Wlin  (no bias) -> bf16 [rows, OUT_F] -------------
__global__ __launch_bounds__(256) void linW_chunk(
    const float* __restrict__ o, int rows, const void* __restrict__ Wlin,
    u16* __restrict__ P, const int* __restrict__ flag_f)
{
  const int wide = *flag_f;
  __shared__ u16 Wl[HID * OUT_F];   // 16 KB
  __shared__ float xt[HID][68];     // 34.8 KB
  for (int i = threadIdx.x; i < HID * OUT_F; i += 256) Wl[i] = ld16(Wlin, i, wide);
  const int base = blockIdx.x * 64;
  for (int i = threadIdx.x; i < 64 * HID; i += 256) {
    int node = i >> 7, k = i & 127;
    int nn = base + node;
    xt[k][node] = (nn < rows) ? fmaxf(o[(size_t)nn * HID + k], 0.f) : 0.f;
  }
  __syncthreads();
  const int ng = threadIdx.x & 15;
  const int cg = threadIdx.x >> 4;
  float acc[4][4];
#pragma unroll
  for (int r = 0; r < 4; ++r)
#pragma unroll
    for (int j = 0; j < 4; ++j) acc[r][j] = 0.f;
#pragma unroll 4
  for (int k = 0; k < HID; ++k) {
    const float4 xv = *(const float4*)&xt[k][ng * 4];
    const ushort4 wv = *(const ushort4*)&Wl[k * OUT_F + cg * 4];
    const float w0 = us2f(wv.x), w1 = us2f(wv.y), w2 = us2f(wv.z), w3 = us2f(wv.w);
    acc[0][0] += xv.x * w0; acc[0][1] += xv.x * w1; acc[0][2] += xv.x * w2; acc[0][3] += xv.x * w3;
    acc[1][0] += xv.y * w0; acc[1][1] += xv.y * w1; acc[1][2] += xv.y * w2; acc[1][3] += xv.y * w3;
    acc[2][0] += xv.z * w0; acc[2][1] += xv.z * w1; acc[2][2] += xv.z * w2; acc[2][3] += xv.z * w3;
    acc[3][0] += xv.w * w0; acc[3][1] += xv.w * w1; acc[3][2] += xv.w * w2; acc[3][3] += xv.w * w3;
  }
#pragma unroll
  for (int r = 0; r < 4; ++r) {
    int nn = base + ng * 4 + r;
    if (nn < rows) {
      ushort4 ov;
      ov.x = f2us(acc[r][0]); ov.y = f2us(acc[r][1]);
      ov.z = f2us(acc[r][2]); ov.w = f2us(acc[r][3]);
      *(ushort4*)&P[(size_t)nn * OUT_F + cg * 4] = ov;
    }
  }
}

// ---- author out chunk: y = relu(o)@Wlin + blin  (width-adaptive store) -----
__global__ __launch_bounds__(256) void final_author_chunk(
    const float* __restrict__ o, int rows, int node0,
    const void* __restrict__ Wlin, const void* __restrict__ blin,
    void* __restrict__ out, const int* __restrict__ flag_f)
{
  const int wide = *flag_f;
  __shared__ u16 Wl[HID * OUT_F];
  __shared__ float xt[HID][68];
  for (int i = threadIdx.x; i < HID * OUT_F; i += 256) Wl[i] = ld16(Wlin, i, wide);
  const int base = blockIdx.x * 64;
  for (int i = threadIdx.x; i < 64 * HID; i += 256) {
    int node = i >> 7, k = i & 127;
    int nn = base + node;
    xt[k][node] = (nn < rows) ? fmaxf(o[(size_t)nn * HID + k], 0.f) : 0.f;
  }
  __syncthreads();
  const int ng = threadIdx.x & 15;
  const int cg = threadIdx.x >> 4;
  float acc[4][4];
#pragma unroll
  for (int r = 0; r < 4; ++r)
#pragma unroll
    for (int j = 0; j < 4; ++j) acc[r][j] = ldf(blin, cg * 4 + j, wide);
#pragma unroll 4
  for (int k = 0; k < HID; ++k) {
    const float4 xv = *(const float4*)&xt[k][ng * 4];
    const ushort4 wv = *(const ushort4*)&Wl[k * OUT_F + cg * 4];
    const float w0 = us2f(wv.x), w1 = us2f(wv.y), w2 = us2f(wv.z), w3 = us2f(wv.w);
    acc[0][0] += xv.x * w0; acc[0][1] += xv.x * w1; acc[0][2] += xv.x * w2; acc[0][3] += xv.x * w3;
    acc[1][0] += xv.y * w0; acc[1][1] += xv.y * w1; acc[1][2] += xv.y * w2; acc[1][3] += xv.y * w3;
    acc[2][0] += xv.z * w0; acc[2][1] += xv.z * w1; acc[2][2] += xv.z * w2; acc[2][3] += xv.z * w3;
    acc[3][0] += xv.w * w0; acc[3][1] += xv.w * w1; acc[3][2] += xv.w * w2; acc[3][3] += xv.w * w3;
  }
#pragma unroll
  for (int r = 0; r < 4; ++r) {
    int nn = base + ng * 4 + r;
    if (nn < rows) {
      size_t oi = (size_t)(node0 + nn) * OUT_F + cg * 4;
      if (wide) {
        float4 ov = {acc[r][0], acc[r][1], acc[r][2], acc[r][3]};
        *(float4*)&((float*)out)[oi] = ov;
      } else {
        ushort4 ov;
        ov.x = f2us(acc[r][0]); ov.y = f2us(acc[r][1]);
        ov.z = f2us(acc[r][2]); ov.w = f2us(acc[r][3]);
        *(ushort4*)&((u16*)out)[oi] = ov;
      }
    }
  }
}

// ---- semantic softmax ------------------------------------------------------
__global__ void score_softmax(const float* __restrict__ S, const void* __restrict__ q,
                              float* __restrict__ attn, float invN,
                              const int* __restrict__ flag_f)
{
  if (threadIdx.x == 0 && blockIdx.x == 0) {
    const int wide = *flag_f;
    float s0 = 0.f, s1 = 0.f;
    for (int c = 0; c < HID; ++c) {
      float qc = ldf(q, c, wide);
      s0 += qc * S[c] * invN;
      s1 += qc * S[HID + c] * invN;
    }
    float m = fmaxf(s0, s1);
    float e0 = __expf(s0 - m), e1 = __expf(s1 - m);
    attn[0] = e0 / (e0 + e1);
    attn[1] = e1 / (e0 + e1);
  }
}

// ---- paper out: y = a0*Pw + a1*Pc + blin  (elem_off = NA*OUT_F) ------------
__global__ __launch_bounds__(256) void combine_paper(
    const u16* __restrict__ Pw, const u16* __restrict__ Pc,
    const float* __restrict__ attn, const void* __restrict__ blin,
    void* __restrict__ out, size_t elem_off, int N,
    const int* __restrict__ flag_f)
{
  int t = blockIdx.x * 256 + threadIdx.x;
  if (t >= N * 16) return;
  const int wide = *flag_f;
  int n = t >> 4, cq = t & 15;
  const float a0 = attn[0], a1 = attn[1];
  size_t i = (size_t)n * OUT_F + cq * 4;
  ushort4 w4 = *(const ushort4*)&Pw[i];
  ushort4 c4 = *(const ushort4*)&Pc[i];
  float v[4];
  v[0] = a0 * us2f(w4.x) + a1 * us2f(c4.x) + ldf(blin, cq * 4 + 0, wide);
  v[1] = a0 * us2f(w4.y) + a1 * us2f(c4.y) + ldf(blin, cq * 4 + 1, wide);
  v[2] = a0 * us2f(w4.z) + a1 * us2f(c4.z) + ldf(blin, cq * 4 + 2, wide);
  v[3] = a0 * us2f(w4.w) + a1 * us2f(c4.w) + ldf(blin, cq * 4 + 3, wide);
  size_t oi = elem_off + i;
  if (wide) {
    float4 ov = {v[0], v[1], v[2], v[3]};
    *(float4*)&((float*)out)[oi] = ov;
  } else {
    ushort4 ov;
    ov.x = f2us(v[0]); ov.y = f2us(v[1]); ov.z = f2us(v[2]); ov.w = f2us(v[3]);
    *(ushort4*)&((u16*)out)[oi] = ov;
  }
}

// ---------------------------------------------------------------------------
extern "C" void kernel_launch(void* const* d_in, const int* in_sizes, int n_in,
                              void* d_out, int out_size, void* d_ws, size_t ws_size,
                              hipStream_t stream)
{
  const int NA = in_sizes[0] / IN_F;   // 100000
  const int NP = in_sizes[1] / IN_F;   // 200000
  const int E_w = in_sizes[2], E_wb = in_sizes[4], E_c = in_sizes[6];
  int Emax = E_w > E_wb ? E_w : E_wb;
  if (E_c > Emax) Emax = E_c;

  const void* x_a   = d_in[0];
  const void* x_p   = d_in[1];
  const int* w_src  = (const int*)d_in[2];
  const int* w_dst  = (const int*)d_in[3];
  const int* wb_src = (const int*)d_in[4];
  const int* wb_dst = (const int*)d_in[5];
  const int* c_src  = (const int*)d_in[6];
  const int* c_dst  = (const int*)d_in[7];
  const void* W_pa  = d_in[8];
  const void* b_pa  = d_in[9];
  const void* W_pp  = d_in[10];
  const void* b_pp  = d_in[11];
  const void* at_s_w  = d_in[12];
  const void* at_d_w  = d_in[13];
  const void* at_s_wb = d_in[14];
  const void* at_d_wb = d_in[15];
  const void* at_s_c  = d_in[16];
  const void* at_d_c  = d_in[17];
  const void* W_k   = d_in[18];
  const void* b_k   = d_in[19];
  const void* q     = d_in[20];
  const void* W_lin = d_in[21];
  const void* b_lin = d_in[22];

  // ---- workspace layout: fixed region (~150 MB) + chunked o accumulator ----
  char* ws = (char*)d_ws;
  size_t off = 0;
  auto alloc = [&](size_t bytes) -> void* {
    void* p = ws + off;
    off += (bytes + 255) & ~(size_t)255;
    return p;
  };
  int*   flag_f = (int*)alloc(4);
  int*   flag_i = (int*)alloc(4);
  float* attn   = (float*)alloc(8 * 4);
  float* S      = (float*)alloc(2 * HID * 4);
  u16*   h_a    = (u16*)alloc((size_t)NA * HID * 2);
  u16*   h_p    = (u16*)alloc((size_t)NP * HID * 2);
  float* aA_ws  = (float*)alloc((size_t)NA * HEADS * 4);
  float* aA_wbd = (float*)alloc((size_t)NA * HEADS * 4);
  float* aP_wd  = (float*)alloc((size_t)NP * HEADS * 4);
  float* aP_wbs = (float*)alloc((size_t)NP * HEADS * 4);
  float* aP_cs  = (float*)alloc((size_t)NP * HEADS * 4);
  float* aP_cd  = (float*)alloc((size_t)NP * HEADS * 4);
  u16*   Pw16   = (u16*)alloc((size_t)NP * OUT_F * 2);
  u16*   Pc16   = (u16*)alloc((size_t)NP * OUT_F * 2);
  // CSR scratch (reused across the three edge types, built sequentially)
  int*   deg    = (int*)alloc((size_t)NP * 4);
  int*   rowptr = (int*)alloc(((size_t)NP + 1) * 4);
  int*   cursor = (int*)alloc((size_t)NP * 4);
  int*   blksum = (int*)alloc(1024);                 // >= ceil(NP/1024) entries
  int*   csrsrc = (int*)alloc((size_t)Emax * 4);
  float* o_f32  = (float*)(ws + off);           // rest of ws, chunked
  size_t o_bytes = (ws_size > off) ? (ws_size - off) : 0;
  long long cap = (long long)(o_bytes / ((size_t)HID * 4));
  int rc = (int)(cap > NP ? NP : cap);
  rc &= ~63;                                     // multiple of 64
  if (rc < 64) rc = 64;                          // last resort; assume ws ok

  // ---- detection ----
  detect_float_width<<<1, 256, 0, stream>>>((const u16*)x_a, 4096, flag_f);
  detect_idx_width<<<1, 256, 0, stream>>>(w_src, 512, flag_i);

  // ---- projections + logits ----
  proj_kernel<<<(NA + 31) / 32, 256, 0, stream>>>(x_a, W_pa, b_pa, h_a, NA, flag_f);
  proj_kernel<<<(NP + 31) / 32, 256, 0, stream>>>(x_p, W_pp, b_pp, h_p, NP, flag_f);
  compute_a2<<<(NA * HEADS + 255) / 256, 256, 0, stream>>>(h_a, at_s_w, at_d_wb, aA_ws, aA_wbd, NA, flag_f);
  compute_a2<<<(NP * HEADS + 255) / 256, 256, 0, stream>>>(h_p, at_d_w, at_s_wb, aP_wd, aP_wbs, NP, flag_f);
  compute_a2<<<(NP * HEADS + 255) / 256, 256, 0, stream>>>(h_p, at_s_c, at_d_c, aP_cs, aP_cd, NP, flag_f);

  hipMemsetAsync(S, 0, 2 * HID * 4, stream);

  auto build_csr = [&](const int* srcp, const int* dstp, int Ecnt, int Ns, int Nd) {
    hipMemsetAsync(deg, 0, (size_t)Nd * 4, stream);
    hist_kernel<<<(Ecnt + 255) / 256, 256, 0, stream>>>(dstp, Ecnt, flag_i, Nd, deg);
    int nb = (Nd + 1023) / 1024;
    scan1_kernel<<<nb, 256, 0, stream>>>(deg, Nd, rowptr, blksum);
    scan2_kernel<<<1, 64, 0, stream>>>(blksum, nb);
    scan3_kernel<<<(Nd + 255) / 256, 256, 0, stream>>>(rowptr, cursor, blksum, Nd, Ecnt);
    reorder_kernel<<<(Ecnt + 255) / 256, 256, 0, stream>>>(srcp, dstp, Ecnt, flag_i, Ns, Nd, cursor, csrsrc);
  };

  // ---- writtenby: paper -> author (direct author output) ----
  build_csr(wb_src, wb_dst, E_wb, NP, NA);
  for (int lo = 0; lo < NA; lo += rc) {
    int rows = (NA - lo < rc) ? (NA - lo) : rc;
    gather_conv<<<(rows + 3) / 4, 256, 0, stream>>>(rowptr, csrsrc, aP_wbs, aA_wbd, h_p, o_f32, lo, rows);
    final_author_chunk<<<(rows + 63) / 64, 256, 0, stream>>>(o_f32, rows, lo, W_lin, b_lin, d_out, flag_f);
  }

  // ---- writes: author -> paper (S0 colsum + Pw) ----
  build_csr(w_src, w_dst, E_w, NA, NP);
  for (int lo = 0; lo < NP; lo += rc) {
    int rows = (NP - lo < rc) ? (NP - lo) : rc;
    gather_conv<<<(rows + 3) / 4, 256, 0, stream>>>(rowptr, csrsrc, aA_ws, aP_wd, h_a, o_f32, lo, rows);
    colsum_chunk<<<512, 256, 0, stream>>>(o_f32, rows, W_k, b_k, S, flag_f);
    linW_chunk<<<(rows + 63) / 64, 256, 0, stream>>>(o_f32, rows, W_lin, Pw16 + (size_t)lo * OUT_F, flag_f);
  }

  // ---- cites: paper -> paper (S1 colsum + Pc) ----
  build_csr(c_src, c_dst, E_c, NP, NP);
  for (int lo = 0; lo < NP; lo += rc) {
    int rows = (NP - lo < rc) ? (NP - lo) : rc;
    gather_conv<<<(rows + 3) / 4, 256, 0, stream>>>(rowptr, csrsrc, aP_cs, aP_cd, h_p, o_f32, lo, rows);
    colsum_chunk<<<512, 256, 0, stream>>>(o_f32, rows, W_k, b_k, S + HID, flag_f);
    linW_chunk<<<(rows + 63) / 64, 256, 0, stream>>>(o_f32, rows, W_lin, Pc16 + (size_t)lo * OUT_F, flag_f);
  }

  // ---- semantic softmax + paper output ----
  score_softmax<<<1, 64, 0, stream>>>(S, q, attn, 1.0f / (float)NP, flag_f);
  combine_paper<<<((size_t)NP * 16 + 255) / 256, 256, 0, stream>>>(Pw16, Pc16, attn, b_lin, d_out, (size_t)NA * OUT_F, NP, flag_f);
}

// Round 3
// 1631.848 us; speedup vs baseline: 2.6198x; 1.4526x over previous
//
#include <hip/hip_runtime.h>
#include <hip/hip_bf16.h>

// HANConv (HANModel). MFMA round (resubmit after infra container failure;
// source audited for OOB/LDS/alignment/hang — unchanged): all GEMM-shaped
// kernels (proj, colsum, linW, final_author) on v_mfma_f32_16x16x32_bf16
// with W transposed+XOR-swizzled in LDS; colsum+linW fused (o read once);
// o stored as relu'd bf16 (halves gather write + GEMM read traffic).
// Gather/CSR/softmax pipeline unchanged from the 2370us version.

#define HEADS 4
#define DH 32
#define HID 128
#define IN_F 128
#define OUT_F 64
#define NEG 0.2f

typedef unsigned short u16;
typedef unsigned int u32;
typedef __attribute__((ext_vector_type(8))) short short8;
typedef __attribute__((ext_vector_type(4))) float f32x4;

__device__ __forceinline__ float us2f(u16 u){ return __uint_as_float(((u32)u) << 16); }
__device__ __forceinline__ u16 f2us(float f){            // f32 -> bf16 RNE
  u32 u = __float_as_uint(f);
  u += 0x7fffu + ((u >> 16) & 1u);
  return (u16)(u >> 16);
}
__device__ __forceinline__ float fin(float v){ return (fabsf(v) < 1e30f) ? v : 0.f; }
__device__ __forceinline__ u16 san16(u16 r){ return (((r >> 7) & 0xff) == 0xff) ? (u16)0 : r; }
// width-adaptive sanitized loads from raw input tensors
__device__ __forceinline__ float ldf(const void* p, size_t i, int wide){
  float v = wide ? ((const float*)p)[i] : us2f(((const u16*)p)[i]);
  return fin(v);
}
__device__ __forceinline__ u16 ld16(const void* p, size_t i, int wide){
  if (wide) return f2us(fin(((const float*)p)[i]));
  return san16(((const u16*)p)[i]);
}
__device__ __forceinline__ int ld_idx(const int* __restrict__ p, int e, int sh, int n){
  int v = p[(size_t)e << sh];
  return v < 0 ? 0 : (v >= n ? n - 1 : v);
}

// ---- detection kernels -----------------------------------------------------
__global__ void detect_float_width(const u16* __restrict__ x, int n, int* __restrict__ flag)
{
  __shared__ int cnt;
  if (threadIdx.x == 0) cnt = 0;
  __syncthreads();
  int local = 0;
  for (int i = threadIdx.x; i < n; i += blockDim.x) {
    int e = (x[i] >> 7) & 0xff;
    if (e == 0 || (e >= 100 && e <= 150)) local++;
  }
  atomicAdd(&cnt, local);
  __syncthreads();
  if (threadIdx.x == 0) *flag = (cnt < (n * 9) / 10) ? 1 : 0;  // 1 = f32
}
__global__ void detect_idx_width(const int* __restrict__ s, int n, int* __restrict__ flag)
{
  __shared__ int any;
  if (threadIdx.x == 0) any = 0;
  __syncthreads();
  for (int i = threadIdx.x; i < n; i += blockDim.x)
    if (s[2 * i + 1] != 0) atomicOr(&any, 1);
  __syncthreads();
  if (threadIdx.x == 0) *flag = any ? 0 : 1;                   // 1 = int64
}

// ---- MFMA GEMM infrastructure ---------------------------------------------
// B staged transposed in LDS: Bt[c][k] bf16, row stride 256B, XOR-swizzle
// byte ^= (c&7)<<4 so 16-lane column-slice ds_read_b128 is ~conflict-free.
template<int N1, int N2>
__device__ __forceinline__ void stage_B(const void* W1, const void* W2, int wide, u16* Bt)
{
  constexpr int NC = N1 + N2;
  for (int i = threadIdx.x; i < 128 * NC; i += 256) {
    int k = i / NC, c = i - k * NC;
    u16 v;
    if constexpr (N2 == 0) {
      v = ld16(W1, (size_t)k * N1 + c, wide);
    } else {
      v = (c < N1) ? ld16(W1, (size_t)k * N1 + c, wide)
                   : ld16(W2, (size_t)k * N2 + (c - N1), wide);
    }
    u32 boff = ((u32)c << 8) + (((u32)(k << 1)) ^ (((u32)(c & 7)) << 4));
    *(u16*)((char*)Bt + boff) = v;
  }
}

// B fragment for tile t, k-step kk: lane c=(t*16+(l&15)), 8 bf16 k-contiguous
__device__ __forceinline__ short8 ldsB(const u16* Bt, int t, int lane, int kk)
{
  const int c = (t << 4) + (lane & 15);
  const u32 boff = ((u32)c << 8) +
      (((u32)(((lane >> 4) << 4) + (kk << 6))) ^ (((u32)(c & 7)) << 4));
  return *(const short8*)((const char*)Bt + boff);
}

// A fragment from raw input x (runtime f32/bf16), row rb, 8 k-contiguous bf16
__device__ __forceinline__ short8 ldA_x(const void* x, size_t rb, int kg, int kk, int wide)
{
  short8 v;
  const size_t base = rb + (size_t)(kg * 8 + kk * 32);
  if (wide) {
    const float* p = (const float*)x + base;
    const float4 f0 = *(const float4*)p;
    const float4 f1 = *(const float4*)(p + 4);
    v[0] = (short)f2us(fin(f0.x)); v[1] = (short)f2us(fin(f0.y));
    v[2] = (short)f2us(fin(f0.z)); v[3] = (short)f2us(fin(f0.w));
    v[4] = (short)f2us(fin(f1.x)); v[5] = (short)f2us(fin(f1.y));
    v[6] = (short)f2us(fin(f1.z)); v[7] = (short)f2us(fin(f1.w));
  } else {
    const short8 raw = *(const short8*)((const u16*)x + base);
#pragma unroll
    for (int j = 0; j < 8; ++j) v[j] = (short)san16((u16)raw[j]);
  }
  return v;
}

// A fragment from our clean bf16 o buffer
__device__ __forceinline__ short8 ldA_o(const u16* o, size_t rb, int kg, int kk)
{
  return *(const short8*)(o + rb + (size_t)(kg * 8 + kk * 32));
}

// ---- projection: h[n,c] = bf16(x[n,:] @ W[:,c] + b[c]) ---------------------
// wave = 16 rows x 128 cols; strip = 64 rows/block; grid-stride over strips.
__global__ __launch_bounds__(256) void proj_mfma(
    const void* __restrict__ x, const void* __restrict__ W,
    const void* __restrict__ b, u16* __restrict__ h, int N,
    const int* __restrict__ flag_f)
{
  const int wide = *flag_f;
  __shared__ u16 Bt[128 * 128];   // 32 KB
  stage_B<HID, 0>(W, nullptr, wide, Bt);
  __syncthreads();
  const int w = threadIdx.x >> 6, lane = threadIdx.x & 63;
  const int r16 = lane & 15, kg = lane >> 4;
  float bv[8];
#pragma unroll
  for (int t = 0; t < 8; ++t) bv[t] = ldf(b, (t << 4) + r16, wide);
  const int nstrips = (N + 63) >> 6;
  for (int sidx = blockIdx.x; sidx < nstrips; sidx += gridDim.x) {
    const int rowbase = (sidx << 6) + (w << 4);
    int arow = rowbase + r16;
    if (arow >= N) arow = N - 1;
    const size_t rb = (size_t)arow * IN_F;
    f32x4 acc[8];
#pragma unroll
    for (int t = 0; t < 8; ++t) acc[t] = (f32x4){0.f, 0.f, 0.f, 0.f};
#pragma unroll
    for (int kk = 0; kk < 4; ++kk) {
      const short8 a = ldA_x(x, rb, kg, kk, wide);
#pragma unroll
      for (int t = 0; t < 8; ++t)
        acc[t] = __builtin_amdgcn_mfma_f32_16x16x32_bf16(a, ldsB(Bt, t, lane, kk), acc[t], 0, 0, 0);
    }
#pragma unroll
    for (int t = 0; t < 8; ++t) {
      const int col = (t << 4) + r16;
#pragma unroll
      for (int j = 0; j < 4; ++j) {
        const int row = rowbase + (kg << 2) + j;
        if (row < N) h[(size_t)row * HID + col] = f2us(acc[t][j] + bv[t]);
      }
    }
  }
}

// ---- fused post: relu'd o (bf16) -> {tanh-colsum via Wk,bk -> S} + {P=o@Wlin}
__global__ __launch_bounds__(256) void fused_post(
    const u16* __restrict__ o, int rows, const void* __restrict__ Wk,
    const void* __restrict__ bk, const void* __restrict__ Wlin,
    float* __restrict__ S, u16* __restrict__ P,
    const int* __restrict__ flag_f)
{
  const int wide = *flag_f;
  __shared__ u16 Bt[192 * 128];   // 48 KB  (cols 0-127 = Wk, 128-191 = Wlin)
  __shared__ float sred[4][HID];  // 2 KB
  stage_B<HID, OUT_F>(Wk, Wlin, wide, Bt);
  __syncthreads();
  const int w = threadIdx.x >> 6, lane = threadIdx.x & 63;
  const int r16 = lane & 15, kg = lane >> 4;
  float bkv[8];
#pragma unroll
  for (int t = 0; t < 8; ++t) bkv[t] = ldf(bk, (t << 4) + r16, wide);
  float scs[8] = {0.f, 0.f, 0.f, 0.f, 0.f, 0.f, 0.f, 0.f};
  const int nstrips = (rows + 63) >> 6;
  for (int sidx = blockIdx.x; sidx < nstrips; sidx += gridDim.x) {
    const int rowbase = (sidx << 6) + (w << 4);
    int arow = rowbase + r16;
    if (arow >= rows) arow = rows - 1;
    const size_t rb = (size_t)arow * HID;
    f32x4 acc[12];
#pragma unroll
    for (int t = 0; t < 12; ++t) acc[t] = (f32x4){0.f, 0.f, 0.f, 0.f};
#pragma unroll
    for (int kk = 0; kk < 4; ++kk) {
      const short8 a = ldA_o(o, rb, kg, kk);
#pragma unroll
      for (int t = 0; t < 12; ++t)
        acc[t] = __builtin_amdgcn_mfma_f32_16x16x32_bf16(a, ldsB(Bt, t, lane, kk), acc[t], 0, 0, 0);
    }
    // semantic colsum (Wk tiles 0-7): S[c] += tanh(acc + bk), valid rows only
#pragma unroll
    for (int t = 0; t < 8; ++t) {
#pragma unroll
      for (int j = 0; j < 4; ++j) {
        const int row = rowbase + (kg << 2) + j;
        if (row < rows) scs[t] += tanhf(acc[t][j] + bkv[t]);
      }
    }
    // P (Wlin tiles 8-11), no bias
#pragma unroll
    for (int t = 8; t < 12; ++t) {
      const int col = ((t - 8) << 4) + r16;
#pragma unroll
      for (int j = 0; j < 4; ++j) {
        const int row = rowbase + (kg << 2) + j;
        if (row < rows) P[(size_t)row * OUT_F + col] = f2us(acc[t][j]);
      }
    }
  }
  // reduce colsum: kg-groups share a column -> shfl over kg -> per-wave row
#pragma unroll
  for (int t = 0; t < 8; ++t) {
    float v = scs[t];
    v += __shfl_xor(v, 16);
    v += __shfl_xor(v, 32);
    if (kg == 0) sred[w][(t << 4) + r16] = v;
  }
  __syncthreads();
  if (threadIdx.x < HID) {
    float v = sred[0][threadIdx.x] + sred[1][threadIdx.x] +
              sred[2][threadIdx.x] + sred[3][threadIdx.x];
    atomicAdd(&S[threadIdx.x], v);
  }
}

// ---- author out: y = o(bf16,relu'd) @ Wlin + blin  (width-adaptive) --------
__global__ __launch_bounds__(256) void author_mfma(
    const u16* __restrict__ o, int rows, int node0,
    const void* __restrict__ Wlin, const void* __restrict__ blin,
    void* __restrict__ out, const int* __restrict__ flag_f)
{
  const int wide = *flag_f;
  __shared__ u16 Bt[64 * 128];    // 16 KB
  stage_B<OUT_F, 0>(Wlin, nullptr, wide, Bt);
  __syncthreads();
  const int w = threadIdx.x >> 6, lane = threadIdx.x & 63;
  const int r16 = lane & 15, kg = lane >> 4;
  float bv[4];
#pragma unroll
  for (int t = 0; t < 4; ++t) bv[t] = ldf(blin, (t << 4) + r16, wide);
  const int nstrips = (rows + 63) >> 6;
  for (int sidx = blockIdx.x; sidx < nstrips; sidx += gridDim.x) {
    const int rowbase = (sidx << 6) + (w << 4);
    int arow = rowbase + r16;
    if (arow >= rows) arow = rows - 1;
    const size_t rb = (size_t)arow * HID;
    f32x4 acc[4];
#pragma unroll
    for (int t = 0; t < 4; ++t) acc[t] = (f32x4){0.f, 0.f, 0.f, 0.f};
#pragma unroll
    for (int kk = 0; kk < 4; ++kk) {
      const short8 a = ldA_o(o, rb, kg, kk);
#pragma unroll
      for (int t = 0; t < 4; ++t)
        acc[t] = __builtin_amdgcn_mfma_f32_16x16x32_bf16(a, ldsB(Bt, t, lane, kk), acc[t], 0, 0, 0);
    }
#pragma unroll
    for (int t = 0; t < 4; ++t) {
      const int col = (t << 4) + r16;
#pragma unroll
      for (int j = 0; j < 4; ++j) {
        const int row = rowbase + (kg << 2) + j;
        if (row < rows) {
          const float val = acc[t][j] + bv[t];
          const size_t oi = (size_t)(node0 + row) * OUT_F + col;
          if (wide) ((float*)out)[oi] = val;
          else      ((u16*)out)[oi] = f2us(val);
        }
      }
    }
  }
}

// ---- per-node logits for two att vectors -----------------------------------
__global__ __launch_bounds__(256) void compute_a2(
    const u16* __restrict__ h, const void* __restrict__ att1,
    const void* __restrict__ att2, float* __restrict__ a1,
    float* __restrict__ a2, int N, const int* __restrict__ flag_f)
{
  const int wide = *flag_f;
  __shared__ float s1[HID], s2[HID];
  if (threadIdx.x < HID) {
    s1[threadIdx.x] = ldf(att1, threadIdx.x, wide);
    s2[threadIdx.x] = ldf(att2, threadIdx.x, wide);
  }
  __syncthreads();
  int t = blockIdx.x * 256 + threadIdx.x;
  if (t >= N * HEADS) return;
  int n = t >> 2, hh = t & 3;
  const u16* p = h + (size_t)n * HID + hh * DH;
  float acc1 = 0.f, acc2 = 0.f;
#pragma unroll
  for (int d = 0; d < DH; ++d) {
    float f = us2f(p[d]);
    acc1 += f * s1[hh * DH + d];
    acc2 += f * s2[hh * DH + d];
  }
  a1[t] = acc1;
  a2[t] = acc2;
}

// ---- CSR build -------------------------------------------------------------
__global__ __launch_bounds__(256) void hist_kernel(
    const int* __restrict__ dst, int E, const int* __restrict__ flag_i,
    int Nd, int* __restrict__ deg)
{
  int e = blockIdx.x * 256 + threadIdx.x;
  if (e >= E) return;
  int sh = *flag_i;
  int d = ld_idx(dst, e, sh, Nd);
  atomicAdd(&deg[d], 1);
}

__global__ __launch_bounds__(256) void scan1_kernel(
    const int* __restrict__ deg, int Nd, int* __restrict__ rowptr,
    int* __restrict__ blksum)
{
  __shared__ int ssum[256];
  int base = blockIdx.x * 1024;
  int t = threadIdx.x;
  int idx0 = base + t * 4;
  int v[4];
#pragma unroll
  for (int j = 0; j < 4; ++j) v[j] = (idx0 + j < Nd) ? deg[idx0 + j] : 0;
  int tsum = v[0] + v[1] + v[2] + v[3];
  ssum[t] = tsum;
  __syncthreads();
  for (int ofs = 1; ofs < 256; ofs <<= 1) {
    int x = (t >= ofs) ? ssum[t - ofs] : 0;
    __syncthreads();
    ssum[t] += x;
    __syncthreads();
  }
  if (t == 255) blksum[blockIdx.x] = ssum[255];
  int run = ssum[t] - tsum;
#pragma unroll
  for (int j = 0; j < 4; ++j) {
    if (idx0 + j < Nd) rowptr[idx0 + j] = run;
    run += v[j];
  }
}

__global__ void scan2_kernel(int* __restrict__ blksum, int nb)
{
  if (threadIdx.x == 0 && blockIdx.x == 0) {
    int run = 0;
    for (int b = 0; b < nb; ++b) { int t = blksum[b]; blksum[b] = run; run += t; }
  }
}

__global__ __launch_bounds__(256) void scan3_kernel(
    int* __restrict__ rowptr, int* __restrict__ cursor,
    const int* __restrict__ blksum, int Nd, int E)
{
  int i = blockIdx.x * 256 + threadIdx.x;
  if (i < Nd) {
    int v = rowptr[i] + blksum[i >> 10];
    rowptr[i] = v;
    cursor[i] = v;
  }
  if (i == 0) rowptr[Nd] = E;
}

__global__ __launch_bounds__(256) void reorder_kernel(
    const int* __restrict__ src, const int* __restrict__ dst, int E,
    const int* __restrict__ flag_i, int Ns, int Nd,
    int* __restrict__ cursor, int* __restrict__ csr_src)
{
  int e = blockIdx.x * 256 + threadIdx.x;
  if (e >= E) return;
  int sh = *flag_i;
  int d = ld_idx(dst, e, sh, Nd);
  int s = ld_idx(src, e, sh, Ns);
  int pos = atomicAdd(&cursor[d], 1);
  csr_src[pos] = s;
}

// ---- gather edge conv: one wave per dst node, lane = 2 channels ------------
// writes relu'd bf16 o row once; rows with no edges write 0.
__global__ __launch_bounds__(256) void gather_conv(
    const int* __restrict__ rowptr, const int* __restrict__ csr_src,
    const float* __restrict__ a_s, const float* __restrict__ a_d,
    const u16* __restrict__ h_src, u16* __restrict__ o,
    int lo, int rows)
{
  int wid = (blockIdx.x * 256 + threadIdx.x) >> 6;
  if (wid >= rows) return;
  int n = lo + wid;
  int lane = threadIdx.x & 63;
  int hh = lane >> 4;
  int start = rowptr[n], end = rowptr[n + 1];
  float ad = a_d[n * HEADS + hh];
  float m = -1e30f;
  for (int e = start; e < end; ++e) {
    int s = csr_src[e];
    float al = a_s[s * HEADS + hh] + ad;
    al = (al > 0.f) ? al : NEG * al;
    m = fmaxf(m, al);
  }
  float den = 0.f, n0 = 0.f, n1 = 0.f;
  for (int e = start; e < end; ++e) {
    int s = csr_src[e];
    float al = a_s[s * HEADS + hh] + ad;
    al = (al > 0.f) ? al : NEG * al;
    float ex = __expf(al - m);
    den += ex;
    const u16* hp = h_src + (size_t)s * HID + 2 * lane;
    n0 += ex * us2f(hp[0]);
    n1 += ex * us2f(hp[1]);
  }
  float inv = 1.f / (den + 1e-16f);
  ushort2 st;
  st.x = f2us(fmaxf(n0 * inv, 0.f));
  st.y = f2us(fmaxf(n1 * inv, 0.f));
  *(ushort2*)(o + (size_t)wid * HID + 2 * lane) = st;
}

// ---- semantic softmax ------------------------------------------------------
__global__ void score_softmax(const float* __restrict__ S, const void* __restrict__ q,
                              float* __restrict__ attn, float invN,
                              const int* __restrict__ flag_f)
{
  if (threadIdx.x == 0 && blockIdx.x == 0) {
    const int wide = *flag_f;
    float s0 = 0.f, s1 = 0.f;
    for (int c = 0; c < HID; ++c) {
      float qc = ldf(q, c, wide);
      s0 += qc * S[c] * invN;
      s1 += qc * S[HID + c] * invN;
    }
    float m = fmaxf(s0, s1);
    float e0 = __expf(s0 - m), e1 = __expf(s1 - m);
    attn[0] = e0 / (e0 + e1);
    attn[1] = e1 / (e0 + e1);
  }
}

// ---- paper out: y = a0*Pw + a1*Pc + blin  (elem_off = NA*OUT_F) ------------
__global__ __launch_bounds__(256) void combine_paper(
    const u16* __restrict__ Pw, const u16* __restrict__ Pc,
    const float* __restrict__ attn, const void* __restrict__ blin,
    void* __restrict__ out, size_t elem_off, int N,
    const int* __restrict__ flag_f)
{
  int t = blockIdx.x * 256 + threadIdx.x;
  if (t >= N * 16) return;
  const int wide = *flag_f;
  int n = t >> 4, cq = t & 15;
  const float a0 = attn[0], a1 = attn[1];
  size_t i = (size_t)n * OUT_F + cq * 4;
  ushort4 w4 = *(const ushort4*)&Pw[i];
  ushort4 c4 = *(const ushort4*)&Pc[i];
  float v[4];
  v[0] = a0 * us2f(w4.x) + a1 * us2f(c4.x) + ldf(blin, cq * 4 + 0, wide);
  v[1] = a0 * us2f(w4.y) + a1 * us2f(c4.y) + ldf(blin, cq * 4 + 1, wide);
  v[2] = a0 * us2f(w4.z) + a1 * us2f(c4.z) + ldf(blin, cq * 4 + 2, wide);
  v[3] = a0 * us2f(w4.w) + a1 * us2f(c4.w) + ldf(blin, cq * 4 + 3, wide);
  size_t oi = elem_off + i;
  if (wide) {
    float4 ov = {v[0], v[1], v[2], v[3]};
    *(float4*)&((float*)out)[oi] = ov;
  } else {
    ushort4 ov;
    ov.x = f2us(v[0]); ov.y = f2us(v[1]); ov.z = f2us(v[2]); ov.w = f2us(v[3]);
    *(ushort4*)&((u16*)out)[oi] = ov;
  }
}

// ---------------------------------------------------------------------------
extern "C" void kernel_launch(void* const* d_in, const int* in_sizes, int n_in,
                              void* d_out, int out_size, void* d_ws, size_t ws_size,
                              hipStream_t stream)
{
  const int NA = in_sizes[0] / IN_F;   // 100000
  const int NP = in_sizes[1] / IN_F;   // 200000
  const int E_w = in_sizes[2], E_wb = in_sizes[4], E_c = in_sizes[6];
  int Emax = E_w > E_wb ? E_w : E_wb;
  if (E_c > Emax) Emax = E_c;

  const void* x_a   = d_in[0];
  const void* x_p   = d_in[1];
  const int* w_src  = (const int*)d_in[2];
  const int* w_dst  = (const int*)d_in[3];
  const int* wb_src = (const int*)d_in[4];
  const int* wb_dst = (const int*)d_in[5];
  const int* c_src  = (const int*)d_in[6];
  const int* c_dst  = (const int*)d_in[7];
  const void* W_pa  = d_in[8];
  const void* b_pa  = d_in[9];
  const void* W_pp  = d_in[10];
  const void* b_pp  = d_in[11];
  const void* at_s_w  = d_in[12];
  const void* at_d_w  = d_in[13];
  const void* at_s_wb = d_in[14];
  const void* at_d_wb = d_in[15];
  const void* at_s_c  = d_in[16];
  const void* at_d_c  = d_in[17];
  const void* W_k   = d_in[18];
  const void* b_k   = d_in[19];
  const void* q     = d_in[20];
  const void* W_lin = d_in[21];
  const void* b_lin = d_in[22];

  // ---- workspace layout ----
  char* ws = (char*)d_ws;
  size_t off = 0;
  auto alloc = [&](size_t bytes) -> void* {
    void* p = ws + off;
    off += (bytes + 255) & ~(size_t)255;
    return p;
  };
  int*   flag_f = (int*)alloc(4);
  int*   flag_i = (int*)alloc(4);
  float* attn   = (float*)alloc(8 * 4);
  float* S      = (float*)alloc(2 * HID * 4);
  u16*   h_a    = (u16*)alloc((size_t)NA * HID * 2);
  u16*   h_p    = (u16*)alloc((size_t)NP * HID * 2);
  float* aA_ws  = (float*)alloc((size_t)NA * HEADS * 4);
  float* aA_wbd = (float*)alloc((size_t)NA * HEADS * 4);
  float* aP_wd  = (float*)alloc((size_t)NP * HEADS * 4);
  float* aP_wbs = (float*)alloc((size_t)NP * HEADS * 4);
  float* aP_cs  = (float*)alloc((size_t)NP * HEADS * 4);
  float* aP_cd  = (float*)alloc((size_t)NP * HEADS * 4);
  u16*   Pw16   = (u16*)alloc((size_t)NP * OUT_F * 2);
  u16*   Pc16   = (u16*)alloc((size_t)NP * OUT_F * 2);
  int*   deg    = (int*)alloc((size_t)NP * 4);
  int*   rowptr = (int*)alloc(((size_t)NP + 1) * 4);
  int*   cursor = (int*)alloc((size_t)NP * 4);
  int*   blksum = (int*)alloc(1024);
  int*   csrsrc = (int*)alloc((size_t)Emax * 4);
  u16*   o16    = (u16*)(ws + off);             // rest of ws, chunked, bf16
  size_t o_bytes = (ws_size > off) ? (ws_size - off) : 0;
  long long cap = (long long)(o_bytes / ((size_t)HID * 2));
  int rc = (int)(cap > NP ? NP : cap);
  rc &= ~63;
  if (rc < 64) rc = 64;

  // ---- detection ----
  detect_float_width<<<1, 256, 0, stream>>>((const u16*)x_a, 4096, flag_f);
  detect_idx_width<<<1, 256, 0, stream>>>(w_src, 512, flag_i);

  // ---- projections + logits ----
  {
    int gA = (NA + 63) / 64; if (gA > 1024) gA = 1024;
    int gP = (NP + 63) / 64; if (gP > 1024) gP = 1024;
    proj_mfma<<<gA, 256, 0, stream>>>(x_a, W_pa, b_pa, h_a, NA, flag_f);
    proj_mfma<<<gP, 256, 0, stream>>>(x_p, W_pp, b_pp, h_p, NP, flag_f);
  }
  compute_a2<<<(NA * HEADS + 255) / 256, 256, 0, stream>>>(h_a, at_s_w, at_d_wb, aA_ws, aA_wbd, NA, flag_f);
  compute_a2<<<(NP * HEADS + 255) / 256, 256, 0, stream>>>(h_p, at_d_w, at_s_wb, aP_wd, aP_wbs, NP, flag_f);
  compute_a2<<<(NP * HEADS + 255) / 256, 256, 0, stream>>>(h_p, at_s_c, at_d_c, aP_cs, aP_cd, NP, flag_f);

  hipMemsetAsync(S, 0, 2 * HID * 4, stream);

  auto build_csr = [&](const int* srcp, const int* dstp, int Ecnt, int Ns, int Nd) {
    hipMemsetAsync(deg, 0, (size_t)Nd * 4, stream);
    hist_kernel<<<(Ecnt + 255) / 256, 256, 0, stream>>>(dstp, Ecnt, flag_i, Nd, deg);
    int nb = (Nd + 1023) / 1024;
    scan1_kernel<<<nb, 256, 0, stream>>>(deg, Nd, rowptr, blksum);
    scan2_kernel<<<1, 64, 0, stream>>>(blksum, nb);
    scan3_kernel<<<(Nd + 255) / 256, 256, 0, stream>>>(rowptr, cursor, blksum, Nd, Ecnt);
    reorder_kernel<<<(Ecnt + 255) / 256, 256, 0, stream>>>(srcp, dstp, Ecnt, flag_i, Ns, Nd, cursor, csrsrc);
  };

  // ---- writtenby: paper -> author (direct author output) ----
  build_csr(wb_src, wb_dst, E_wb, NP, NA);
  for (int lo = 0; lo < NA; lo += rc) {
    int rows = (NA - lo < rc) ? (NA - lo) : rc;
    gather_conv<<<(rows + 3) / 4, 256, 0, stream>>>(rowptr, csrsrc, aP_wbs, aA_wbd, h_p, o16, lo, rows);
    int g = (rows + 63) / 64; if (g > 1024) g = 1024;
    author_mfma<<<g, 256, 0, stream>>>(o16, rows, lo, W_lin, b_lin, d_out, flag_f);
  }

  // ---- writes: author -> paper (S0 colsum + Pw) ----
  build_csr(w_src, w_dst, E_w, NA, NP);
  for (int lo = 0; lo < NP; lo += rc) {
    int rows = (NP - lo < rc) ? (NP - lo) : rc;
    gather_conv<<<(rows + 3) / 4, 256, 0, stream>>>(rowptr, csrsrc, aA_ws, aP_wd, h_a, o16, lo, rows);
    int g = (rows + 63) / 64; if (g > 768) g = 768;
    fused_post<<<g, 256, 0, stream>>>(o16, rows, W_k, b_k, W_lin, S, Pw16 + (size_t)lo * OUT_F, flag_f);
  }

  // ---- cites: paper -> paper (S1 colsum + Pc) ----
  build_csr(c_src, c_dst, E_c, NP, NP);
  for (int lo = 0; lo < NP; lo += rc) {
    int rows = (NP - lo < rc) ? (NP - lo) : rc;
    gather_conv<<<(rows + 3) / 4, 256, 0, stream>>>(rowptr, csrsrc, aP_cs, aP_cd, h_p, o16, lo, rows);
    int g = (rows + 63) / 64; if (g > 768) g = 768;
    fused_post<<<g, 256, 0, stream>>>(o16, rows, W_k, b_k, W_lin, S + HID, Pc16 + (size_t)lo * OUT_F, flag_f);
  }

  // ---- semantic softmax + paper output ----
  score_softmax<<<1, 64, 0, stream>>>(S, q, attn, 1.0f / (float)NP, flag_f);
  combine_paper<<<((size_t)NP * 16 + 255) / 256, 256, 0, stream>>>(Pw16, Pc16, attn, b_lin, d_out, (size_t)NA * OUT_F, NP, flag_f);
}